// Round 5
// baseline (443.643 us; speedup 1.0000x reference)
//
#include <hip/hip_runtime.h>

typedef unsigned short u16;
typedef unsigned int   u32;
typedef __attribute__((ext_vector_type(8))) short s16x8;
typedef __attribute__((ext_vector_type(4))) float f32x4;

constexpr int Bc = 2, Sc = 2048, DIMc = 2048, NHc = 16, HDc = 128, Tc = Bc * Sc;
constexpr float LAMBDA_INIT_C = 0.2f;   // 0.8 - 0.6*exp(0)

__device__ __forceinline__ u16 f2bf(float f) {
  union { float f; u32 u; } v; v.f = f;
  u32 r = v.u + 0x7fffu + ((v.u >> 16) & 1u);   // RNE
  return (u16)(r >> 16);
}
__device__ __forceinline__ float bf2f(u16 b) {
  union { u32 u; float f; } v; v.u = ((u32)b) << 16;
  return v.f;
}
__device__ __forceinline__ f32x4 mfma16(s16x8 a, s16x8 b, f32x4 c) {
  return __builtin_amdgcn_mfma_f32_16x16x32_bf16(a, b, c, 0, 0, 0);
}

typedef const __attribute__((address_space(1))) u32 gq32;
typedef __attribute__((address_space(3))) u32 lq32;
__device__ __forceinline__ void cp16(const u16* g, u16* l) {
  __builtin_amdgcn_global_load_lds((gq32*)g, (lq32*)l, 16, 0, 0);
}

// ---------------- fp32 -> bf16 convert: x + 4 contiguous weight tensors --------
__global__ void cvt_all_kernel(const float* __restrict__ x,
                               const float* __restrict__ wq, const float* __restrict__ wk,
                               const float* __restrict__ wv, const float* __restrict__ wo,
                               u16* __restrict__ xb, u16* __restrict__ wb) {
  const int i = blockIdx.x * 256 + threadIdx.x;
  constexpr int NX = Tc * DIMc / 4;       // 2^21 float4
  constexpr int PW = DIMc * DIMc / 4;     // 2^20 float4 per weight
  float4 v; uint2* dst;
  if (i < NX) {
    v = ((const float4*)x)[i];
    dst = ((uint2*)xb) + i;
  } else {
    const int j = i - NX;
    const int which = j >> 20;
    const int jj = j & (PW - 1);
    const float* src = which == 0 ? wq : which == 1 ? wk : which == 2 ? wv : wo;
    v = ((const float4*)src)[jj];
    dst = ((uint2*)wb) + j;
  }
  union { u16 u[4]; uint2 p; } o;
  o.u[0] = f2bf(v.x); o.u[1] = f2bf(v.y); o.u[2] = f2bf(v.z); o.u[3] = f2bf(v.w);
  *dst = o.p;
}

// ---------------- merged QKV projection GEMM with fused RoPE / V-transpose -----
// grid (48, 32). n-global selects {Q,K,V}. Epilogue:
//   Q/K: RoPE in-register (pairs are adjacent lanes -> shfl_xor(1)), write
//        qr/kr[bh][s][128] (Q pre-scaled 0.125).
//   V:   pack 4 consecutive tokens (C-layout rows) -> 8B store to vt[bh][d][s].
__global__ __launch_bounds__(256) void gemm_qkv(const u16* __restrict__ A,
                                                const u16* __restrict__ Wq,
                                                const u16* __restrict__ Wk,
                                                const u16* __restrict__ Wv,
                                                const float* __restrict__ fc,
                                                u16* __restrict__ qr,
                                                u16* __restrict__ kr,
                                                u16* __restrict__ vt) {
  constexpr int K = DIMc, N = DIMc;
  __shared__ u16 lA[128 * 32];
  __shared__ u16 lB[128 * 32];
  const int nglob = blockIdx.x * 128;
  const int which = nglob >> 11;
  const u16* Bw = which == 0 ? Wq : which == 1 ? Wk : Wv;
  const int nbase = nglob & (N - 1);
  const int mbase = blockIdx.y * 128;

  const int tid  = threadIdx.x;
  const int lane = tid & 63;
  const int w    = tid >> 6;
  const int wrow = (w >> 1) * 64;
  const int wcol = (w & 1) * 64;
  const int l15  = lane & 15;
  const int quad = lane >> 4;

  f32x4 acc[4][4];
#pragma unroll
  for (int i = 0; i < 4; i++)
#pragma unroll
    for (int j = 0; j < 4; j++) acc[i][j] = (f32x4){0.f, 0.f, 0.f, 0.f};

  const int srow = w * 32 + (lane >> 2);
  const int scol = (lane & 3) * 8;
  const u16* gA = A  + (size_t)(mbase + srow) * K + scol;
  const u16* gB = Bw + (size_t)(nbase + srow) * K + scol;
  u16* sA = lA + srow * 32 + scol;
  u16* sB = lB + srow * 32 + scol;

  for (int kb = 0; kb < K; kb += 32) {
    __syncthreads();
    cp16(gA + kb,                  sA);
    cp16(gA + kb + (size_t)16 * K, sA + 16 * 32);
    cp16(gB + kb,                  sB);
    cp16(gB + kb + (size_t)16 * K, sB + 16 * 32);
    __syncthreads();
    s16x8 af[4], bfr[4];
#pragma unroll
    for (int i = 0; i < 4; i++)
      af[i] = *(const s16x8*)(lA + (wrow + i * 16 + l15) * 32 + quad * 8);
#pragma unroll
    for (int j = 0; j < 4; j++)
      bfr[j] = *(const s16x8*)(lB + (wcol + j * 16 + l15) * 32 + quad * 8);
#pragma unroll
    for (int i = 0; i < 4; i++)
#pragma unroll
      for (int j = 0; j < 4; j++) acc[i][j] = mfma16(af[i], bfr[j], acc[i][j]);
  }

  const int hh = nbase >> 7;           // head (128-wide tiles = one head each)
  const int bb = mbase >> 11;          // batch
  const size_t bhOff = (size_t)(bb * NHc + hh);

  if (which < 2) {
    // RoPE epilogue: d = wcol + j*16 + l15; pair partner is lane^1.
    u16* outp = which == 0 ? qr : kr;
    const float scale = which == 0 ? 0.125f : 1.0f;   // Q pre-scaled 1/sqrt(64)
#pragma unroll
    for (int i = 0; i < 4; i++) {
      const int m0 = mbase + wrow + i * 16 + quad * 4;
#pragma unroll
      for (int j = 0; j < 4; j++) {
        const int d = wcol + j * 16 + l15;
        const int p = d >> 1;
        const float sign = (d & 1) ? 1.f : -1.f;
#pragma unroll
        for (int r = 0; r < 4; r++) {
          const int s = (m0 + r) & (Sc - 1);
          const float4 f4 = *(const float4*)(fc + (size_t)(s * 64 + p) * 4);
          const float c = f4.x * scale, sn = f4.z * scale;
          const float xv = acc[i][j][r];
          const float prt = __shfl_xor(xv, 1);
          outp[(bhOff * Sc + s) * HDc + d] = f2bf(c * xv + sign * sn * prt);
        }
      }
    }
  } else {
    // V transpose epilogue: 4 consecutive tokens at fixed d -> one 8B store.
#pragma unroll
    for (int i = 0; i < 4; i++) {
      const int s0 = (mbase + wrow + i * 16 + quad * 4) & (Sc - 1);
#pragma unroll
      for (int j = 0; j < 4; j++) {
        const int d = wcol + j * 16 + l15;
        union { u16 u[4]; uint2 pck; } o4;
#pragma unroll
        for (int r = 0; r < 4; r++) o4.u[r] = f2bf(acc[i][j][r]);
        *(uint2*)(vt + (bhOff * HDc + d) * Sc + s0) = o4.pck;
      }
    }
  }
}

// ---------------- bf16 GEMM, fp32 out ----------------
__global__ __launch_bounds__(256) void gemm_bt(const u16* __restrict__ A,
                                               const u16* __restrict__ Bw,
                                               float* __restrict__ Cf,
                                               int M, int N, int K) {
  __shared__ u16 lA[128 * 32];
  __shared__ u16 lB[128 * 32];
  const int tid  = threadIdx.x;
  const int lane = tid & 63;
  const int w    = tid >> 6;
  const int mbase = blockIdx.y * 128;
  const int nbase = blockIdx.x * 128;
  const int wrow = (w >> 1) * 64;
  const int wcol = (w & 1) * 64;
  const int l15  = lane & 15;
  const int quad = lane >> 4;

  f32x4 acc[4][4];
#pragma unroll
  for (int i = 0; i < 4; i++)
#pragma unroll
    for (int j = 0; j < 4; j++) acc[i][j] = (f32x4){0.f, 0.f, 0.f, 0.f};

  const int srow = w * 32 + (lane >> 2);
  const int scol = (lane & 3) * 8;
  const u16* gA = A  + (size_t)(mbase + srow) * K + scol;
  const u16* gB = Bw + (size_t)(nbase + srow) * K + scol;
  u16* sA = lA + srow * 32 + scol;
  u16* sB = lB + srow * 32 + scol;

  for (int kb = 0; kb < K; kb += 32) {
    __syncthreads();
    cp16(gA + kb,                  sA);
    cp16(gA + kb + (size_t)16 * K, sA + 16 * 32);
    cp16(gB + kb,                  sB);
    cp16(gB + kb + (size_t)16 * K, sB + 16 * 32);
    __syncthreads();
    s16x8 af[4], bfr[4];
#pragma unroll
    for (int i = 0; i < 4; i++)
      af[i] = *(const s16x8*)(lA + (wrow + i * 16 + l15) * 32 + quad * 8);
#pragma unroll
    for (int j = 0; j < 4; j++)
      bfr[j] = *(const s16x8*)(lB + (wcol + j * 16 + l15) * 32 + quad * 8);
#pragma unroll
    for (int i = 0; i < 4; i++)
#pragma unroll
      for (int j = 0; j < 4; j++) acc[i][j] = mfma16(af[i], bfr[j], acc[i][j]);
  }

#pragma unroll
  for (int i = 0; i < 4; i++) {
    const int m0 = mbase + wrow + i * 16 + quad * 4;
#pragma unroll
    for (int j = 0; j < 4; j++) {
      const int n0 = nbase + wcol + j * 16 + l15;
#pragma unroll
      for (int r = 0; r < 4; r++) Cf[(size_t)(m0 + r) * N + n0] = acc[i][j][r];
    }
  }
}

// ---------------- fused causal diff-attention -> permuted Y ----------------
// Balanced pairing: block j handles 64-row q-tiles j and 31-j; 64-key chunks
// (two independent 32-key subs per barrier). K rows are PERMUTED at staging
// (per-lane global source addr; LDS dest stays linear) with
// m(s) = (s&3) + ((s>>2)&3)*8 + ((s>>4)<<2), and QK^T is computed transposed
// (A=K, B=Q) so the score C-layout keys at lane (quad,l15) are exactly keys
// quad*8+j -- identical to the PV A-fragment layout and VB's key order.
__global__ __launch_bounds__(256, 2) void diff_attn_kernel(
    const u16* __restrict__ qr, const u16* __restrict__ kr, const u16* __restrict__ vt,
    const float* __restrict__ lq1, const float* __restrict__ lk1,
    const float* __restrict__ lq2, const float* __restrict__ lk2,
    const float* __restrict__ subw, u16* __restrict__ Y) {
  __shared__ u16 KB[2][8192];   // [buf][sub*512 + dblk*32 + slot][8]
  __shared__ u16 VB[2][8192];   // [buf][sub*512 + keyq*128 + d][8]

  const int h = blockIdx.y, b = blockIdx.z, jb = blockIdx.x;
  const int bh = b * NHc + h;
  const int tid = threadIdx.x;
  const int w = tid >> 6, lane = tid & 63;
  const int l15 = lane & 15, quad = lane >> 4;

  const u16* krb = kr + (size_t)bh * Sc * HDc;
  const u16* vtb = vt + (size_t)bh * HDc * Sc;

  float lp1 = lq1[lane] * lk1[lane];
  float lp2 = lq2[lane] * lk2[lane];
#pragma unroll
  for (int m = 32; m; m >>= 1) { lp1 += __shfl_xor(lp1, m); lp2 += __shfl_xor(lp2, m); }
  const float lam = __expf(lp1) - __expf(lp2) + LAMBDA_INIT_C;

  float wsub[8];
#pragma unroll
  for (int dn = 0; dn < 8; dn++) wsub[dn] = subw[dn * 16 + l15];

  // staging address precompute
  size_t offK[4], offV[4];
  int dstO[4];
#pragma unroll
  for (int oo = 0; oo < 4; oo++) {
    const int n = w * 256 + oo * 64 + lane;
    const int s = n & 31, dblk = (n >> 5) & 15, sub = n >> 9;
    const int mkey = (s & 3) + ((s >> 2) & 3) * 8 + ((s >> 4) << 2);  // key permutation
    offK[oo] = (size_t)(sub * 32 + mkey) * HDc + dblk * 8;
    offV[oo] = (size_t)(n & 127) * Sc + (sub * 32 + ((n >> 7) & 3) * 8);
    dstO[oo] = n * 8;
  }

  for (int ph = 0; ph < 2; ph++) {
    const int t = ph ? (31 - jb) : jb;
    const int rowbase = t * 64 + w * 16;
    const int nc = t + 1;   // 64-key chunks

    const u16* qp = qr + ((size_t)bh * Sc + rowbase + l15) * HDc + quad * 8;
    s16x8 qa[2][2];
    qa[0][0] = *(const s16x8*)(qp);
    qa[0][1] = *(const s16x8*)(qp + 32);
    qa[1][0] = *(const s16x8*)(qp + 64);
    qa[1][1] = *(const s16x8*)(qp + 96);

    f32x4 o[2][8];
#pragma unroll
    for (int st = 0; st < 2; st++)
#pragma unroll
      for (int dn = 0; dn < 8; dn++) o[st][dn] = (f32x4){0.f, 0.f, 0.f, 0.f};
    float lpart[2] = { 0.f, 0.f };

    __syncthreads();  // protect buffers from previous phase's readers
#pragma unroll
    for (int oo = 0; oo < 4; oo++) cp16(krb + offK[oo], KB[0] + dstO[oo]);
#pragma unroll
    for (int oo = 0; oo < 4; oo++) cp16(vtb + offV[oo], VB[0] + dstO[oo]);

    for (int c = 0; c < nc; c++) {
      __syncthreads();
      if (c + 1 < nc) {
        const int kb1 = (c + 1) * 64;
        u16* Kn = KB[(c + 1) & 1];
        u16* Vn = VB[(c + 1) & 1];
#pragma unroll
        for (int oo = 0; oo < 4; oo++) cp16(krb + (size_t)kb1 * HDc + offK[oo], Kn + dstO[oo]);
#pragma unroll
        for (int oo = 0; oo < 4; oo++) cp16(vtb + offV[oo] + kb1, Vn + dstO[oo]);
      }
      const u16* Kb = KB[c & 1];
      const u16* Vb = VB[c & 1];
      const int kb = c * 64;
      const bool diag = (c == nc - 1);

#pragma unroll
      for (int sub = 0; sub < 2; sub++) {
        if (diag && sub == 1 && w < 2) continue;  // fully-masked sub, wave-uniform skip

        // QK^T transposed: A=K (permuted rows), B=Q
        f32x4 sc[2][2];
#pragma unroll
        for (int st = 0; st < 2; st++)
#pragma unroll
          for (int kt = 0; kt < 2; kt++) sc[st][kt] = (f32x4){0.f, 0.f, 0.f, 0.f};
#pragma unroll
        for (int st = 0; st < 2; st++)
#pragma unroll
          for (int kh = 0; kh < 2; kh++) {
            const int base = sub * 512 + (st * 8 + kh * 4 + quad) * 32;
#pragma unroll
            for (int kt = 0; kt < 2; kt++) {
              const s16x8 kf = *(const s16x8*)(Kb + (size_t)(base + kt * 16 + l15) * 8);
              sc[st][kt] = mfma16(kf, qa[st][kh], sc[st][kt]);
            }
          }

        // in-lane exp + mask + partial-l + pack (keys at this lane = quad*8+j)
        s16x8 pa[2];
#pragma unroll
        for (int st = 0; st < 2; st++) {
          float p[8];
#pragma unroll
          for (int kt = 0; kt < 2; kt++)
#pragma unroll
            for (int r = 0; r < 4; r++) p[kt * 4 + r] = __expf(sc[st][kt][r]);
          if (diag) {
            const int qrow = rowbase + l15;
            const int kb0 = kb + sub * 32 + quad * 8;
#pragma unroll
            for (int j8 = 0; j8 < 8; j8++)
              if (kb0 + j8 > qrow) p[j8] = 0.f;
          }
          float sm = 0.f;
#pragma unroll
          for (int j8 = 0; j8 < 8; j8++) sm += p[j8];
          lpart[st] += sm;
          union { u16 us[8]; s16x8 vv; } pk;
#pragma unroll
          for (int j8 = 0; j8 < 8; j8++) pk.us[j8] = f2bf(p[j8]);
          pa[st] = pk.vv;
        }

        // PV
#pragma unroll
        for (int dn = 0; dn < 8; dn++) {
          const s16x8 vf =
              *(const s16x8*)(Vb + (size_t)(sub * 512 + quad * 128 + dn * 16 + l15) * 8);
          o[0][dn] = mfma16(pa[0], vf, o[0][dn]);
          o[1][dn] = mfma16(pa[1], vf, o[1][dn]);
        }
      }
    }

    // epilogue: reduce l partials, combine streams, RMSNorm(128), *0.8, write
    float lL0 = lpart[0], lL1 = lpart[1];
    lL0 += __shfl_xor(lL0, 16); lL0 += __shfl_xor(lL0, 32);
    lL1 += __shfl_xor(lL1, 16); lL1 += __shfl_xor(lL1, 32);
    const float inv1 = 1.f / lL0;
    const float inv2 = lam / lL1;
    float i1C[4], i2C[4];
#pragma unroll
    for (int r = 0; r < 4; r++) {
      i1C[r] = __shfl(inv1, quad * 4 + r, 16);
      i2C[r] = __shfl(inv2, quad * 4 + r, 16);
    }
    float yv[8][4], ss[4] = { 0.f, 0.f, 0.f, 0.f };
#pragma unroll
    for (int dn = 0; dn < 8; dn++)
#pragma unroll
      for (int r = 0; r < 4; r++) {
        const float y = o[0][dn][r] * i1C[r] - o[1][dn][r] * i2C[r];
        yv[dn][r] = y;
        ss[r] += y * y;
      }
#pragma unroll
    for (int r = 0; r < 4; r++) {
#pragma unroll
      for (int mm = 1; mm < 16; mm <<= 1) ss[r] += __shfl_xor(ss[r], mm);
    }
    float scl[4];
#pragma unroll
    for (int r = 0; r < 4; r++) scl[r] = rsqrtf(ss[r] * (1.f / 128.f) + 1e-5f) * 0.8f;

    u16* yrow = Y + ((size_t)(b * Sc + h * 128 + t * 4 + w)) * 2048;
#pragma unroll
    for (int dn = 0; dn < 8; dn++)
#pragma unroll
      for (int r = 0; r < 4; r++)
        yrow[(quad * 4 + r) * 128 + dn * 16 + l15] = f2bf(yv[dn][r] * scl[r] * wsub[dn]);
  }
}

// ---------------- host launcher ----------------
extern "C" void kernel_launch(void* const* d_in, const int* in_sizes, int n_in,
                              void* d_out, int out_size, void* d_ws, size_t ws_size,
                              hipStream_t stream) {
  const float* x    = (const float*)d_in[0];
  const float* fc   = (const float*)d_in[1];
  const float* wq   = (const float*)d_in[2];
  const float* wk   = (const float*)d_in[3];
  const float* wv   = (const float*)d_in[4];
  const float* wo   = (const float*)d_in[5];
  const float* lq1  = (const float*)d_in[6];
  const float* lk1  = (const float*)d_in[7];
  const float* lq2  = (const float*)d_in[8];
  const float* lk2  = (const float*)d_in[9];
  const float* subw = (const float*)d_in[10];
  float* out = (float*)d_out;

  char* ws = (char*)d_ws;
  constexpr size_t SZ_X  = (size_t)Tc * DIMc * 2;        // 16 MB
  constexpr size_t SZ_W  = (size_t)DIMc * DIMc * 2;      // 8 MB
  constexpr size_t SZ_T  = (size_t)Tc * DIMc * 2;        // 16 MB
  u16* xb  = (u16*)(ws);
  u16* wqb = (u16*)(ws + SZ_X);                          // wq,wk,wv,wo contiguous
  u16* wkb = (u16*)(ws + SZ_X + SZ_W);
  u16* wvb = (u16*)(ws + SZ_X + 2 * SZ_W);
  u16* wob = (u16*)(ws + SZ_X + 3 * SZ_W);
  u16* qr  = (u16*)(ws + SZ_X + 4 * SZ_W);
  u16* kr  = (u16*)(ws + SZ_X + 4 * SZ_W + SZ_T);
  u16* vt  = (u16*)(ws + SZ_X + 4 * SZ_W + 2 * SZ_T);
  u16* Y   = (u16*)(ws + SZ_X + 4 * SZ_W + 3 * SZ_T);

  // 1) fp32 -> bf16 (one dispatch: x + 4 weights)
  cvt_all_kernel<<<(Tc * DIMc / 4 + 4 * DIMc * DIMc / 4) / 256, 256, 0, stream>>>(
      x, wq, wk, wv, wo, xb, wqb);

  // 2) merged QKV projection GEMM with fused RoPE (Q,K) and V-transpose epilogues
  gemm_qkv<<<dim3(48, Tc / 128), 256, 0, stream>>>(xb, wqb, wkb, wvb, fc, qr, kr, vt);

  // 3) fused causal differential attention -> permuted Y
  diff_attn_kernel<<<dim3(16, NHc, Bc), 256, 0, stream>>>(
      qr, kr, vt, lq1, lk1, lq2, lk2, subw, Y);

  // 4) output GEMM (fp32 out)
  gemm_bt<<<dim3(DIMc / 128, Tc / 128), 256, 0, stream>>>(Y, wob, out, Tc, DIMc, DIMc);
}